// Round 1
// 339.071 us; speedup vs baseline: 1.1124x; 1.1124x over previous
//
#include <hip/hip_runtime.h>
#include <cstdint>
#include <cstddef>

#define HDIM 128
#define DDIM 64
#define NTYPES 5
#define NGRAPHS 16
#define PCHUNK 128   // edges per pooling block
#define EPB 64       // edges per block (one per lane)
#define APW 8        // atoms per wave in atom_proj

typedef __attribute__((ext_vector_type(8))) short short8;   // 8 bf16
typedef __attribute__((ext_vector_type(4))) float f32x4;

static __device__ __forceinline__ short8 as_s8(uint4 u) {
    return __builtin_bit_cast(short8, u);
}

// fast silu: v_rcp_f32 (rel err ~1e-7) instead of precise-division sequence
static __device__ __forceinline__ float silu_f(float v) {
    return v * __builtin_amdgcn_rcpf(1.0f + __expf(-v));
}

static __device__ __forceinline__ float4 ld4(const float* p) {
    return *reinterpret_cast<const float4*>(p);
}

static __device__ __forceinline__ void st4(float* p, float4 v) {
    *reinterpret_cast<float4*>(p) = v;
}

static __device__ __forceinline__ float4 add4(float4 a, float4 b) {
    return make_float4(a.x + b.x, a.y + b.y, a.z + b.z, a.w + b.w);
}

static __device__ __forceinline__ void silu_acc4(float4& s, float4 v) {
    s.x += silu_f(v.x);
    s.y += silu_f(v.y);
    s.z += silu_f(v.z);
    s.w += silu_f(v.w);
}

// ---- bf16 pack/unpack (round-to-nearest-even; feature j0+0 in low half) ----
static __device__ __forceinline__ unsigned int bf16r(float f) {
    unsigned int u = __float_as_uint(f);
    return (u + 0x7FFFu + ((u >> 16) & 1u)) >> 16;
}
static __device__ __forceinline__ uint4 pack8(const float* f) {
    uint4 r;
    r.x = bf16r(f[0]) | (bf16r(f[1]) << 16);
    r.y = bf16r(f[2]) | (bf16r(f[3]) << 16);
    r.z = bf16r(f[4]) | (bf16r(f[5]) << 16);
    r.w = bf16r(f[6]) | (bf16r(f[7]) << 16);
    return r;
}
static __device__ __forceinline__ void unpack8(uint4 u, float4& a, float4& b) {
    a.x = __uint_as_float(u.x << 16);
    a.y = __uint_as_float(u.x & 0xFFFF0000u);
    a.z = __uint_as_float(u.y << 16);
    a.w = __uint_as_float(u.y & 0xFFFF0000u);
    b.x = __uint_as_float(u.z << 16);
    b.y = __uint_as_float(u.z & 0xFFFF0000u);
    b.z = __uint_as_float(u.w << 16);
    b.w = __uint_as_float(u.w & 0xFFFF0000u);
}

// split fp32 -> bf16 hi + bf16 lo (lo = v - float(hi)); hi+lo ~ 16 mantissa bits
static __device__ __forceinline__ void hilo8(const float* f, uint4& h, uint4& lo) {
    h = pack8(f);
    float4 a, b;
    unpack8(h, a, b);
    float g[8] = {f[0] - a.x, f[1] - a.y, f[2] - a.z, f[3] - a.w,
                  f[4] - b.x, f[5] - b.y, f[6] - b.z, f[7] - b.w};
    lo = pack8(g);
}

// XCD-affinity swizzle (heuristic blk%8 -> XCD round-robin; validated r7:
// layer_k FETCH 82 -> 25.7 MB).
static __device__ __forceinline__ int xcd_logical_block() {
    int chunk = (int)(gridDim.x >> 3);
    return (int)(blockIdx.x & 7) * chunk + (int)(blockIdx.x >> 3);
}

// ---------------- CSR build ----------------
__global__ void __launch_bounds__(256) count_k(const int* __restrict__ bdst,
                                               int* __restrict__ cnt, int BE) {
    int i = blockIdx.x * 256 + threadIdx.x;
    if (i < BE)
        __hip_atomic_fetch_add(&cnt[bdst[i]], 1, __ATOMIC_RELAXED, __HIP_MEMORY_SCOPE_AGENT);
}

__global__ void __launch_bounds__(256) bsum_k(const int* __restrict__ cnt,
                                              int* __restrict__ bsum, int E) {
    __shared__ int red[256];
    int t = threadIdx.x;
    int i = blockIdx.x * 256 + t;
    red[t] = (i < E) ? cnt[i] : 0;
    __syncthreads();
    #pragma unroll
    for (int off = 128; off > 0; off >>= 1) {
        if (t < off) red[t] += red[t + off];
        __syncthreads();
    }
    if (t == 0) bsum[blockIdx.x] = red[0];
}

__global__ void __launch_bounds__(1024) bscan_k(const int* __restrict__ bsum,
                                                int* __restrict__ bpre, int NB) {
    __shared__ int sh[1024];
    int t = threadIdx.x;
    int v0 = (t < NB) ? bsum[t] : 0;
    sh[t] = v0;
    __syncthreads();
    for (int off = 1; off < 1024; off <<= 1) {
        int v = (t >= off) ? sh[t - off] : 0;
        __syncthreads();
        sh[t] += v;
        __syncthreads();
    }
    if (t < NB) bpre[t] = sh[t] - v0;
}

__global__ void __launch_bounds__(256) offs_k(const int* __restrict__ cnt,
                                              const int* __restrict__ bpre,
                                              int* __restrict__ offs,
                                              int* __restrict__ cursor, int E) {
    __shared__ int sh[256];
    int t = threadIdx.x;
    int i = blockIdx.x * 256 + t;
    int v0 = (i < E) ? cnt[i] : 0;
    sh[t] = v0;
    __syncthreads();
    for (int off = 1; off < 256; off <<= 1) {
        int v = (t >= off) ? sh[t - off] : 0;
        __syncthreads();
        sh[t] += v;
        __syncthreads();
    }
    int ex = sh[t] - v0 + bpre[blockIdx.x];
    if (i < E) { offs[i] = ex; cursor[i] = ex; }
    if (i == E - 1) offs[E] = ex + v0;
}

__global__ void __launch_bounds__(256) scatter_k(const int* __restrict__ bsrc,
                                                 const int* __restrict__ bdst,
                                                 int* __restrict__ cursor,
                                                 int* __restrict__ srclist, int BE) {
    int i = blockIdx.x * 256 + threadIdx.x;
    if (i < BE) {
        int d = bdst[i];
        int p = __hip_atomic_fetch_add(&cursor[d], 1, __ATOMIC_RELAXED,
                                       __HIP_MEMORY_SCOPE_AGENT);
        srclist[p] = bsrc[i];
    }
}

// tt for BOTH layers
__global__ void __launch_bounds__(64) tt2_k(const float* __restrict__ emb,
                                            const float* __restrict__ mw1,
                                            const float* __restrict__ mb1,
                                            float* __restrict__ tt) {
    int b = blockIdx.x;
    int l = b / NTYPES, t = b % NTYPES, j = threadIdx.x;
    const float* embl = emb + (size_t)l * NTYPES * DDIM + (size_t)t * DDIM;
    const float* w1 = mw1 + (size_t)l * 192 * DDIM;
    float s = mb1[l * DDIM + j];
    #pragma unroll 8
    for (int k = 0; k < DDIM; ++k)
        s = fmaf(embl[k], w1[(HDIM + k) * DDIM + j], s);
    tt[(size_t)b * DDIM + j] = s;
}

// Fused weights: W2u[l] = mw2[l] @ uw1[l][0:64]; b2u[l] = mb2[l] @ uw1[l][0:64].
__global__ void __launch_bounds__(64) fuse_k(const float* __restrict__ mw2,
                                             const float* __restrict__ mb2,
                                             const float* __restrict__ uw1,
                                             float* __restrict__ w2u,
                                             float* __restrict__ b2u) {
    int l = blockIdx.x >> 6, k = blockIdx.x & 63, j = threadIdx.x;
    const float* w2 = mw2 + (size_t)l * DDIM * DDIM;
    const float* u1 = uw1 + (size_t)l * 128 * DDIM;   // rows 0..63 = mm part
    float s = 0.f;
    #pragma unroll 8
    for (int t = 0; t < DDIM; ++t)
        s = fmaf(w2[k * DDIM + t], u1[(size_t)t * DDIM + j], s);
    w2u[(size_t)l * DDIM * DDIM + (size_t)k * DDIM + j] = s;
    if (k == 0) {
        float b = 0.f;
        #pragma unroll 8
        for (int t = 0; t < DDIM; ++t)
            b = fmaf(mb2[l * DDIM + t], u1[(size_t)t * DDIM + j], b);
        b2u[l * DDIM + j] = b;
    }
}

// ---------------- MFMA fragment machinery ----------------
// B-frag pack layout for mfma_f32_16x16x32_bf16 (B is K32 x N16):
//   lane l holds B[ks*32 + (l>>4)*8 + i][jt*16 + (l&15)], i=0..7, as 8 bf16.
// Buffer index: ((jt*2+ks)*64 + lane)*2 + {0=hi,1=lo}.  One 64x64 matrix = 1024 uint4.
__global__ void __launch_bounds__(64) packall_k(const float* __restrict__ w2u,
                                                const float* __restrict__ uw1,
                                                const float* __restrict__ uw2,
                                                const float* __restrict__ mw1,
                                                uint4* __restrict__ fw2u,
                                                uint4* __restrict__ fu1b,
                                                uint4* __restrict__ fu2,
                                                uint4* __restrict__ fp) {
    int b = blockIdx.x;
    int mat = b >> 3, jt = (b >> 1) & 3, ks = b & 1, l = threadIdx.x;
    const float* src;
    uint4* dst;
    switch (mat) {
        case 0: src = w2u;                         dst = fw2u;        break;  // layer0 W2u
        case 1: src = w2u + 4096;                  dst = fw2u + 1024; break;  // layer1 W2u
        case 2: src = uw1 + 64 * 64;               dst = fu1b;        break;  // layer0 uw1[64:128]
        case 3: src = uw1 + 128 * 64 + 64 * 64;    dst = fu1b + 1024; break;  // layer1 uw1[64:128]
        case 4: src = uw2;                         dst = fu2;         break;  // layer0 uw2
        case 5: src = uw2 + 4096;                  dst = fu2 + 1024;  break;  // layer1 uw2
        case 6: src = mw1 + (size_t)192 * 64;      dst = fp;          break;  // layer1 mw1[0:64]   (pd part)
        default: src = mw1 + (size_t)192 * 64 + 64 * 64; dst = fp + 1024; break; // layer1 mw1[64:128] (ps part)
    }
    int k0 = ks * 32 + (l >> 4) * 8;
    int j = jt * 16 + (l & 15);
    float f[8];
    #pragma unroll
    for (int i = 0; i < 8; ++i) f[i] = src[(size_t)(k0 + i) * 64 + j];
    uint4 h, lo;
    hilo8(f, h, lo);
    size_t di = ((size_t)(jt * 2 + ks) * 64 + l) * 2;
    dst[di] = h;
    dst[di + 1] = lo;
}

// LDS A-tile: [64 rows][8 slots of 16B] bf16, XOR-swizzled within the row so the
// 128B-stride fragment reads don't 16-way bank-conflict (G4).
static __device__ __forceinline__ int slotIdx(int row, int slot) {
    return row * 8 + (slot ^ (row & 7));
}

// A-frag (M16 x K32): lane l holds A[rowBase + (l&15)][ks*32 + (l>>4)*8 + i], i=0..7.
static __device__ __forceinline__ short8 ldFragA(const uint4* buf, int rowBase, int lane, int ks) {
    int row = rowBase + (lane & 15);
    int slot = ks * 4 + (lane >> 4);
    return as_s8(buf[slotIdx(row, slot)]);
}

static __device__ __forceinline__ void loadB(const uint4* __restrict__ frag, int jt, int lane,
                                             short8& h0, short8& h1, short8& l0, short8& l1) {
    const uint4* p0 = frag + ((size_t)(jt * 2 + 0) * 64 + lane) * 2;
    const uint4* p1 = frag + ((size_t)(jt * 2 + 1) * 64 + lane) * 2;
    h0 = as_s8(p0[0]); l0 = as_s8(p0[1]);
    h1 = as_s8(p1[0]); l1 = as_s8(p1[1]);
}

// one 16x16 output tile, K=64, split-precision: Ahi*Bhi + Alo*Bhi + Ahi*Blo
static __device__ __forceinline__ f32x4 gemm_tile(const uint4* Ahi, const uint4* Alo,
        int rowBase, int lane,
        short8 bh0, short8 bh1, short8 bl0, short8 bl1, f32x4 acc) {
    short8 ah0 = ldFragA(Ahi, rowBase, lane, 0);
    short8 ah1 = ldFragA(Ahi, rowBase, lane, 1);
    short8 al0 = ldFragA(Alo, rowBase, lane, 0);
    short8 al1 = ldFragA(Alo, rowBase, lane, 1);
    acc = __builtin_amdgcn_mfma_f32_16x16x32_bf16(ah0, bh0, acc, 0, 0, 0);
    acc = __builtin_amdgcn_mfma_f32_16x16x32_bf16(ah1, bh1, acc, 0, 0, 0);
    acc = __builtin_amdgcn_mfma_f32_16x16x32_bf16(al0, bh0, acc, 0, 0, 0);
    acc = __builtin_amdgcn_mfma_f32_16x16x32_bf16(al1, bh1, acc, 0, 0, 0);
    acc = __builtin_amdgcn_mfma_f32_16x16x32_bf16(ah0, bl0, acc, 0, 0, 0);
    acc = __builtin_amdgcn_mfma_f32_16x16x32_bf16(ah1, bl1, acc, 0, 0, 0);
    return acc;
}

// ---------------- atom-side projection: wave-per-8-atoms, lane = feature ----------------
__global__ void __launch_bounds__(256) atom_proj_k(
    const float* __restrict__ AF, const float* __restrict__ iw1,
    float* __restrict__ pa, float* __restrict__ qa, float* __restrict__ na, int N) {
    int lane = threadIdx.x & 63;
    int w = __builtin_amdgcn_readfirstlane((int)(threadIdx.x >> 6));
    int abase = blockIdx.x * (4 * APW) + w * APW;
    if (abase >= N) return;

    float accp[APW], accq[APW], nrm[APW];
    #pragma unroll
    for (int a = 0; a < APW; ++a) { accp[a] = 0.f; accq[a] = 0.f; nrm[a] = 0.f; }

    #pragma unroll 4
    for (int k = 0; k < HDIM; k += 4) {
        float wt[4], wb[4];
        #pragma unroll
        for (int kk = 0; kk < 4; ++kk) {
            wt[kk] = iw1[(size_t)(k + kk) * DDIM + lane];
            wb[kk] = iw1[(size_t)(HDIM + k + kk) * DDIM + lane];
        }
        #pragma unroll
        for (int a = 0; a < APW; ++a) {
            int aa = min(abase + a, N - 1);           // wave-uniform
            float4 hv = ld4(AF + (size_t)aa * HDIM + k);
            accp[a] = fmaf(hv.x, wt[0], accp[a]);
            accp[a] = fmaf(hv.y, wt[1], accp[a]);
            accp[a] = fmaf(hv.z, wt[2], accp[a]);
            accp[a] = fmaf(hv.w, wt[3], accp[a]);
            accq[a] = fmaf(hv.x, wb[0], accq[a]);
            accq[a] = fmaf(hv.y, wb[1], accq[a]);
            accq[a] = fmaf(hv.z, wb[2], accq[a]);
            accq[a] = fmaf(hv.w, wb[3], accq[a]);
            nrm[a] = fmaf(hv.x, hv.x, nrm[a]);
            nrm[a] = fmaf(hv.y, hv.y, nrm[a]);
            nrm[a] = fmaf(hv.z, hv.z, nrm[a]);
            nrm[a] = fmaf(hv.w, hv.w, nrm[a]);
        }
    }
    #pragma unroll
    for (int a = 0; a < APW; ++a) {
        int atom = abase + a;
        if (atom < N) {
            pa[(size_t)atom * DDIM + lane] = accp[a];
            qa[(size_t)atom * DDIM + lane] = accq[a];
            if (lane == 0) na[atom] = sqrtf(nrm[a]);
        }
    }
}

// ---------------- bond init (from atom projections) + layer-0 proj ----------------
// 512 threads = 8 waves; lane = bond; wave w owns 8-feature slice [8w, 8w+8).
// ps written as packed bf16 (uint4 per 8 features).
__global__ void __launch_bounds__(512) bond_init2_k(
    const float* __restrict__ AF, const int* __restrict__ row, const int* __restrict__ col,
    const float* __restrict__ pa, const float* __restrict__ qa, const float* __restrict__ na,
    const float* __restrict__ b1, const float* __restrict__ w2, const float* __restrict__ b2,
    const float* __restrict__ w1p /*[192][64] layer0 mw1*/,
    float* __restrict__ x, int* __restrict__ bt,
    float* __restrict__ pd, uint4* __restrict__ ps, int E) {
    __shared__ float hbuf[EPB][DDIM + 1];
    __shared__ float dotb[EPB][8];
    int nEB = (E + EPB - 1) / EPB;
    int lb = xcd_logical_block();
    if (lb >= nEB) return;
    int tid = threadIdx.x;
    int lane = tid & 63;
    int w = __builtin_amdgcn_readfirstlane((int)(tid >> 6));   // 0..7
    int e = lb * EPB + lane;
    bool ok = e < E;
    int eidx = ok ? e : 0;
    int r = row[eidx], c = col[eidx];
    int j0 = w * 8;

    // partial dot over K-chunk [16w, 16w+16)
    {
        const float* hi = AF + (size_t)r * HDIM + w * 16;
        const float* hj = AF + (size_t)c * HDIM + w * 16;
        float d = 0.f;
        #pragma unroll
        for (int k = 0; k < 16; k += 4) {
            float4 a4 = ld4(hi + k), b4 = ld4(hj + k);
            d += a4.x * b4.x + a4.y * b4.y + a4.z * b4.z + a4.w * b4.w;
        }
        dotb[lane][w] = d;
    }

    // layer-1 hidden slice: silu(pa[r] + qa[c] + b1)
    {
        const float* pr = pa + (size_t)r * DDIM + j0;
        const float* qc = qa + (size_t)c * DDIM + j0;
        float4 p0 = ld4(pr + 0), p1 = ld4(pr + 4);
        float4 q0 = ld4(qc + 0), q1 = ld4(qc + 4);
        hbuf[lane][j0 + 0] = silu_f(p0.x + q0.x + b1[j0 + 0]);
        hbuf[lane][j0 + 1] = silu_f(p0.y + q0.y + b1[j0 + 1]);
        hbuf[lane][j0 + 2] = silu_f(p0.z + q0.z + b1[j0 + 2]);
        hbuf[lane][j0 + 3] = silu_f(p0.w + q0.w + b1[j0 + 3]);
        hbuf[lane][j0 + 4] = silu_f(p1.x + q1.x + b1[j0 + 4]);
        hbuf[lane][j0 + 5] = silu_f(p1.y + q1.y + b1[j0 + 5]);
        hbuf[lane][j0 + 6] = silu_f(p1.z + q1.z + b1[j0 + 6]);
        hbuf[lane][j0 + 7] = silu_f(p1.w + q1.w + b1[j0 + 7]);
    }
    __syncthreads();

    if (w == 0) {
        float dot = dotb[lane][0] + dotb[lane][1] + dotb[lane][2] + dotb[lane][3]
                  + dotb[lane][4] + dotb[lane][5] + dotb[lane][6] + dotb[lane][7];
        float nr = fmaxf(na[r], 1e-8f), nc = fmaxf(na[c], 1e-8f);
        float sim = dot / (nr * nc);
        int t = 0;
        if (sim > 0.8f) t = 1;
        if (sim > 0.9f) t = 2;
        if (sim < 0.3f) t = 3;
        if (ok) bt[e] = t;
    }

    // layer-2: x = h @ w2 + b2 (K=64 from LDS)
    float o[8];
    #pragma unroll
    for (int jj = 0; jj < 8; ++jj) o[jj] = b2[j0 + jj];
    #pragma unroll 4
    for (int k = 0; k < DDIM; ++k) {
        float hk = hbuf[lane][k];
        const float* wk = w2 + (size_t)k * DDIM + j0;
        #pragma unroll
        for (int jj = 0; jj < 8; ++jj) o[jj] = fmaf(hk, wk[jj], o[jj]);
    }
    if (ok) {
        float* xr = x + (size_t)e * DDIM + j0;
        st4(xr + 0, make_float4(o[0], o[1], o[2], o[3]));
        st4(xr + 4, make_float4(o[4], o[5], o[6], o[7]));
    }
    __syncthreads();            // all reads of hbuf (h) done
    #pragma unroll
    for (int jj = 0; jj < 8; ++jj) hbuf[lane][j0 + jj] = o[jj];   // x row
    __syncthreads();

    // proj (layer 0): pd = x@W1[0:64] (fp32), ps = x@W1[64:128] (bf16 packed)
    float apd[8], aps[8];
    #pragma unroll
    for (int jj = 0; jj < 8; ++jj) { apd[jj] = 0.f; aps[jj] = 0.f; }
    #pragma unroll 4
    for (int k = 0; k < DDIM; ++k) {
        float xk = hbuf[lane][k];
        const float* wd = w1p + (size_t)k * DDIM + j0;
        const float* wsv = w1p + (size_t)(DDIM + k) * DDIM + j0;
        #pragma unroll
        for (int jj = 0; jj < 8; ++jj) {
            apd[jj] = fmaf(xk, wd[jj], apd[jj]);
            aps[jj] = fmaf(xk, wsv[jj], aps[jj]);
        }
    }
    if (ok) {
        float* pr = pd + (size_t)e * DDIM + j0;
        st4(pr + 0, make_float4(apd[0], apd[1], apd[2], apd[3]));
        st4(pr + 4, make_float4(apd[4], apd[5], apd[6], apd[7]));
        ps[(size_t)e * 8 + w] = pack8(aps);
    }
}

// proj (x from global) — fallback path only (used if ws too small for pd2/ps2)
__global__ void __launch_bounds__(256) proj_k(const float* __restrict__ x,
                                              const float* __restrict__ w1 /*[192][64]*/,
                                              float* __restrict__ pd, uint4* __restrict__ ps,
                                              int E) {
    int lane = threadIdx.x & 63;
    int w = __builtin_amdgcn_readfirstlane((int)(threadIdx.x >> 6));
    int e = blockIdx.x * EPB + lane;
    bool ok = e < E;
    int eidx = ok ? e : 0;
    int j0 = w * 16;
    const float* xr = x + (size_t)eidx * DDIM;

    float apd[16], aps[16];
    #pragma unroll
    for (int jj = 0; jj < 16; ++jj) { apd[jj] = 0.f; aps[jj] = 0.f; }
    #pragma unroll 2
    for (int c = 0; c < 16; ++c) {
        float4 v = ld4(xr + c * 4);
        float xv[4] = {v.x, v.y, v.z, v.w};
        #pragma unroll
        for (int kk = 0; kk < 4; ++kk) {
            int k = c * 4 + kk;
            const float* wd = w1 + (size_t)k * DDIM + j0;
            const float* wsv = w1 + (size_t)(DDIM + k) * DDIM + j0;
            #pragma unroll
            for (int jj = 0; jj < 16; ++jj) {
                apd[jj] = fmaf(xv[kk], wd[jj], apd[jj]);
                aps[jj] = fmaf(xv[kk], wsv[jj], aps[jj]);
            }
        }
    }
    if (ok) {
        float* pr = pd + (size_t)e * DDIM + j0;
        st4(pr + 0,  make_float4(apd[0],  apd[1],  apd[2],  apd[3]));
        st4(pr + 4,  make_float4(apd[4],  apd[5],  apd[6],  apd[7]));
        st4(pr + 8,  make_float4(apd[8],  apd[9],  apd[10], apd[11]));
        st4(pr + 12, make_float4(apd[12], apd[13], apd[14], apd[15]));
        ps[(size_t)e * 8 + 2 * w + 0] = pack8(aps + 0);
        ps[(size_t)e * 8 + 2 * w + 1] = pack8(aps + 8);
    }
}

// ---------------- fused gather + update (+ optional next-layer proj), MFMA version ----
// 512 threads = 8 waves, block = 64 bonds.
// P1: gather s (bf16 ps, fp32 acc) -> inv-scaled hi/lo bf16 in LDS; stage x hi/lo.
// P2: h = silu((inv*s)@W2u + x@Uw1b + ub1 + degflag*b2u)   [24 mfma/wave]
// P3: xnew = x + h@Uw2 + ub2; store; stage xnew hi/lo       [12 mfma/wave]
// P4 (layer0): pdn = xnew@W1d (fp32); psn = bf16(xnew@W1s)  [24 mfma/wave]
// GEMM tiling: wave w -> col-tile jt=w&3 (j=jt*16+lane&15), row-half mh=w>>2.
// D layout (m89-verified): col = lane&15, row = (lane>>4)*4 + reg.
__global__ void __launch_bounds__(512, 4) layer_k(
    float* __restrict__ x, const float* __restrict__ pd, const uint4* __restrict__ ps,
    const float* __restrict__ tt_l, const int* __restrict__ bt,
    const int* __restrict__ offs, const int* __restrict__ srclist,
    const int* __restrict__ cnt,
    const uint4* __restrict__ fW2u, const float* __restrict__ b2u,
    const uint4* __restrict__ fU1b, const float* __restrict__ ub1,
    const uint4* __restrict__ fU2, const float* __restrict__ ub2,
    const uint4* __restrict__ fP /* next-layer proj frags or nullptr */,
    float* __restrict__ pdn, uint4* __restrict__ psn, int E) {
    __shared__ uint4 sAhi[512];   // s / h / psn-staging  (hi)
    __shared__ uint4 sAlo[512];   //                      (lo)
    __shared__ uint4 sXhi[512];   // x / xnew             (hi)
    __shared__ uint4 sXlo[512];   //                      (lo)
    __shared__ float degLDS[64];  // 1.0 if deg>0 else 0.0
    int nEB = (E + EPB - 1) / EPB;
    int lb = xcd_logical_block();
    if (lb >= nEB) return;
    int tid = threadIdx.x;
    int lane = tid & 63;
    int w = __builtin_amdgcn_readfirstlane((int)(tid >> 6));   // 0..7
    int e0 = lb * EPB;

    // ---- P1: stage x + gather (8 threads per bond, 8 features each) ----
    {
        int dl = tid >> 3, q = tid & 7;
        int d = e0 + dl;
        bool ok = d < E;
        int dd = ok ? d : 0;
        int jq = q * 8;
        const float* xr = x + (size_t)dd * DDIM + jq;
        float4 xv0 = ld4(xr + 0), xv1 = ld4(xr + 4);   // issued early, used late
        int dc = cnt[dd];
        const float* pr = pd + (size_t)dd * DDIM + jq;
        const float* tp = tt_l + (size_t)bt[dd] * DDIM + jq;
        float4 b0 = add4(ld4(pr + 0), ld4(tp + 0));
        float4 b1 = add4(ld4(pr + 4), ld4(tp + 4));
        float4 s0 = make_float4(0, 0, 0, 0), s1 = s0;
        int p0 = ok ? offs[d] : 0, p1 = ok ? offs[d + 1] : 0;
        int p = p0;
        for (; p + 4 <= p1; p += 4) {
            uint4 u0 = ps[(size_t)srclist[p + 0] * 8 + q];
            uint4 u1 = ps[(size_t)srclist[p + 1] * 8 + q];
            uint4 u2 = ps[(size_t)srclist[p + 2] * 8 + q];
            uint4 u3 = ps[(size_t)srclist[p + 3] * 8 + q];
            float4 a, b;
            unpack8(u0, a, b);
            silu_acc4(s0, add4(b0, a));
            silu_acc4(s1, add4(b1, b));
            unpack8(u1, a, b);
            silu_acc4(s0, add4(b0, a));
            silu_acc4(s1, add4(b1, b));
            unpack8(u2, a, b);
            silu_acc4(s0, add4(b0, a));
            silu_acc4(s1, add4(b1, b));
            unpack8(u3, a, b);
            silu_acc4(s0, add4(b0, a));
            silu_acc4(s1, add4(b1, b));
        }
        for (; p < p1; ++p) {
            uint4 u0 = ps[(size_t)srclist[p] * 8 + q];
            float4 a, b;
            unpack8(u0, a, b);
            silu_acc4(s0, add4(b0, a));
            silu_acc4(s1, add4(b1, b));
        }
        float inv = 1.0f / fmaxf((float)dc, 1.0f);
        float sv[8] = {s0.x * inv, s0.y * inv, s0.z * inv, s0.w * inv,
                       s1.x * inv, s1.y * inv, s1.z * inv, s1.w * inv};
        float xf[8] = {xv0.x, xv0.y, xv0.z, xv0.w, xv1.x, xv1.y, xv1.z, xv1.w};
        if (!ok) {
            #pragma unroll
            for (int i = 0; i < 8; ++i) { sv[i] = 0.f; xf[i] = 0.f; }
        }
        uint4 h4, l4;
        int si = slotIdx(dl, q);
        hilo8(sv, h4, l4);
        sAhi[si] = h4; sAlo[si] = l4;
        hilo8(xf, h4, l4);
        sXhi[si] = h4; sXlo[si] = l4;
        if (q == 0) degLDS[dl] = (ok && dc > 0) ? 1.0f : 0.0f;
    }
    // preload loop-invariant B-frags (independent of LDS; overlaps barrier wait)
    int jt = w & 3, mh = w >> 2;
    short8 A2h0, A2h1, A2l0, A2l1;   // W2u
    short8 U1h0, U1h1, U1l0, U1l1;   // Uw1b
    loadB(fW2u, jt, lane, A2h0, A2h1, A2l0, A2l1);
    loadB(fU1b, jt, lane, U1h0, U1h1, U1l0, U1l1);
    __syncthreads();

    // ---- P2: h = silu((inv*s)@W2u + x@Uw1b + bias) ----
    int rb0 = mh * 32, rb1 = mh * 32 + 16;
    f32x4 z4 = {0.f, 0.f, 0.f, 0.f};
    f32x4 acc0 = z4, acc1 = z4;
    acc0 = gemm_tile(sAhi, sAlo, rb0, lane, A2h0, A2h1, A2l0, A2l1, acc0);
    acc0 = gemm_tile(sXhi, sXlo, rb0, lane, U1h0, U1h1, U1l0, U1l1, acc0);
    acc1 = gemm_tile(sAhi, sAlo, rb1, lane, A2h0, A2h1, A2l0, A2l1, acc1);
    acc1 = gemm_tile(sXhi, sXlo, rb1, lane, U1h0, U1h1, U1l0, U1l1, acc1);
    __syncthreads();                       // all s/x fragment reads done
    int j = jt * 16 + (lane & 15);
    float ub1j = ub1[j], b2uj = b2u[j];
    unsigned short* hA = (unsigned short*)sAhi;
    unsigned short* lA = (unsigned short*)sAlo;
    #pragma unroll
    for (int r = 0; r < 4; ++r) {
        int row = rb0 + (lane >> 4) * 4 + r;
        float hv = silu_f(acc0[r] + ub1j + degLDS[row] * b2uj);
        unsigned int hb = bf16r(hv);
        float lov = hv - __uint_as_float(hb << 16);
        int ui = (row * 8 + ((j >> 3) ^ (row & 7))) * 8 + (j & 7);
        hA[ui] = (unsigned short)hb;
        lA[ui] = (unsigned short)bf16r(lov);
    }
    #pragma unroll
    for (int r = 0; r < 4; ++r) {
        int row = rb1 + (lane >> 4) * 4 + r;
        float hv = silu_f(acc1[r] + ub1j + degLDS[row] * b2uj);
        unsigned int hb = bf16r(hv);
        float lov = hv - __uint_as_float(hb << 16);
        int ui = (row * 8 + ((j >> 3) ^ (row & 7))) * 8 + (j & 7);
        hA[ui] = (unsigned short)hb;
        lA[ui] = (unsigned short)bf16r(lov);
    }
    __syncthreads();                       // h staged

    // ---- P3: o = h@Uw2 + ub2; xnew = x + o ----
    short8 U2h0, U2h1, U2l0, U2l1;
    loadB(fU2, jt, lane, U2h0, U2h1, U2l0, U2l1);
    f32x4 o0 = z4, o1 = z4;
    o0 = gemm_tile(sAhi, sAlo, rb0, lane, U2h0, U2h1, U2l0, U2l1, o0);
    o1 = gemm_tile(sAhi, sAlo, rb1, lane, U2h0, U2h1, U2l0, U2l1, o1);
    float ub2j = ub2[j];
    bool haveP = (fP != nullptr);
    unsigned short* hX = (unsigned short*)sXhi;
    unsigned short* lX = (unsigned short*)sXlo;
    #pragma unroll
    for (int r = 0; r < 4; ++r) {
        int row = rb0 + (lane >> 4) * 4 + r;
        int e = e0 + row;
        float xvv = (e < E) ? x[(size_t)e * DDIM + j] : 0.f;
        float xn = xvv + o0[r] + ub2j;
        if (e < E) x[(size_t)e * DDIM + j] = xn;
        if (haveP) {
            unsigned int hb = bf16r(xn);
            float lov = xn - __uint_as_float(hb << 16);
            int ui = (row * 8 + ((j >> 3) ^ (row & 7))) * 8 + (j & 7);
            hX[ui] = (unsigned short)hb;
            lX[ui] = (unsigned short)bf16r(lov);
        }
    }
    #pragma unroll
    for (int r = 0; r < 4; ++r) {
        int row = rb1 + (lane >> 4) * 4 + r;
        int e = e0 + row;
        float xvv = (e < E) ? x[(size_t)e * DDIM + j] : 0.f;
        float xn = xvv + o1[r] + ub2j;
        if (e < E) x[(size_t)e * DDIM + j] = xn;
        if (haveP) {
            unsigned int hb = bf16r(xn);
            float lov = xn - __uint_as_float(hb << 16);
            int ui = (row * 8 + ((j >> 3) ^ (row & 7))) * 8 + (j & 7);
            hX[ui] = (unsigned short)hb;
            lX[ui] = (unsigned short)bf16r(lov);
        }
    }
    if (!haveP) return;
    __syncthreads();    // xnew staged; orders P3 A-reads before P4 A-writes

    // ---- P4: next-layer proj. wave w -> 16-col strip of the 128-wide output.
    const uint4* fPw = (w < 4) ? fP : (fP + 1024);
    int jp = w & 3;
    short8 Ph0, Ph1, Pl0, Pl1;
    loadB(fPw, jp, lane, Ph0, Ph1, Pl0, Pl1);
    f32x4 q0 = z4, q1 = z4, q2 = z4, q3 = z4;
    q0 = gemm_tile(sXhi, sXlo, 0,  lane, Ph0, Ph1, Pl0, Pl1, q0);
    q1 = gemm_tile(sXhi, sXlo, 16, lane, Ph0, Ph1, Pl0, Pl1, q1);
    q2 = gemm_tile(sXhi, sXlo, 32, lane, Ph0, Ph1, Pl0, Pl1, q2);
    q3 = gemm_tile(sXhi, sXlo, 48, lane, Ph0, Ph1, Pl0, Pl1, q3);
    if (w < 4) {
        // pdn (fp32), cols jp*16 + (lane&15)
        int jd = jp * 16 + (lane & 15);
        #pragma unroll
        for (int mt = 0; mt < 4; ++mt) {
            f32x4 qq = (mt == 0) ? q0 : (mt == 1) ? q1 : (mt == 2) ? q2 : q3;
            #pragma unroll
            for (int r = 0; r < 4; ++r) {
                int row = mt * 16 + (lane >> 4) * 4 + r;
                int e = e0 + row;
                if (e < E) pdn[(size_t)e * DDIM + jd] = qq[r];
            }
        }
    } else {
        // psn (bf16): stage into sAhi rows then repack as uint4
        int js = jp * 16 + (lane & 15);
        #pragma unroll
        for (int mt = 0; mt < 4; ++mt) {
            f32x4 qq = (mt == 0) ? q0 : (mt == 1) ? q1 : (mt == 2) ? q2 : q3;
            #pragma unroll
            for (int r = 0; r < 4; ++r) {
                int row = mt * 16 + (lane >> 4) * 4 + r;
                int ui = (row * 8 + ((js >> 3) ^ (row & 7))) * 8 + (js & 7);
                hA[ui] = (unsigned short)bf16r(qq[r]);
            }
        }
    }
    __syncthreads();
    {
        int dl = tid >> 3, q = tid & 7;
        int d = e0 + dl;
        if (d < E) psn[(size_t)d * 8 + q] = sAhi[slotIdx(dl, q)];
    }
}

// ---------------- pooling ----------------
__global__ void __launch_bounds__(256) pool_k(
    const float* __restrict__ x, const int* __restrict__ row,
    const int* __restrict__ batch, float* __restrict__ gfeat, int E) {
    int lane = threadIdx.x & 63;
    int esub = threadIdx.x >> 6;       // 0..3
    int e0 = blockIdx.x * PCHUNK;
    int e1 = min(e0 + PCHUNK, E);
    float sum = 0.f;
    int cur = -1;
    for (int e = e0 + esub; e < e1; e += 4) {
        int g = batch[row[e]];         // wave-uniform -> scalar load
        if (g != cur) {
            if (cur >= 0)
                __hip_atomic_fetch_add(&gfeat[cur * DDIM + lane], sum,
                                       __ATOMIC_RELAXED, __HIP_MEMORY_SCOPE_AGENT);
            cur = g;
            sum = 0.f;
        }
        sum += x[(size_t)e * DDIM + lane];
    }
    if (cur >= 0)
        __hip_atomic_fetch_add(&gfeat[cur * DDIM + lane], sum,
                               __ATOMIC_RELAXED, __HIP_MEMORY_SCOPE_AGENT);
}

static __device__ __forceinline__ int lower_bound_bb(const int* __restrict__ row,
                                                     const int* __restrict__ batch,
                                                     int E, int g) {
    int lo = 0, hi = E;
    while (lo < hi) {
        int m = (lo + hi) >> 1;
        if (batch[row[m]] < g) lo = m + 1; else hi = m;
    }
    return lo;
}

__global__ void __launch_bounds__(64) pool_final_k(
    const int* __restrict__ row, const int* __restrict__ batch,
    float* __restrict__ gfeat, int E) {
    int g = blockIdx.x, j = threadIdx.x;
    int s = lower_bound_bb(row, batch, E, g);
    int t = lower_bound_bb(row, batch, E, g + 1);
    float cnt = fmaxf((float)(t - s), 1.0f);
    gfeat[g * DDIM + j] /= cnt;
}

extern "C" void kernel_launch(void* const* d_in, const int* in_sizes, int n_in,
                              void* d_out, int out_size, void* d_ws, size_t ws_size,
                              hipStream_t stream) {
    (void)n_in; (void)out_size;
    const float* AF    = (const float*)d_in[0];
    const int*   batch = (const int*)d_in[3];
    const int*   edge_index      = (const int*)d_in[4];
    const int*   bond_edge_index = (const int*)d_in[5];
    const float* iw1 = (const float*)d_in[6];
    const float* ib1 = (const float*)d_in[7];
    const float* iw2 = (const float*)d_in[8];
    const float* ib2 = (const float*)d_in[9];
    const float* emb = (const float*)d_in[10];
    const float* mw1 = (const float*)d_in[11];
    const float* mb1 = (const float*)d_in[12];
    const float* mw2 = (const float*)d_in[13];
    const float* mb2 = (const float*)d_in[14];
    const float* uw1 = (const float*)d_in[15];
    const float* ub1 = (const float*)d_in[16];
    const float* uw2 = (const float*)d_in[17];
    const float* ub2 = (const float*)d_in[18];

    const int N  = in_sizes[0] / HDIM;
    const int E  = in_sizes[4] / 2;
    const int BE = in_sizes[5] / 2;
    const int NB = (E + 255) / 256;
    const int EB = (E + EPB - 1) / EPB;
    const int AB = (N + 4 * APW - 1) / (4 * APW);   // atom blocks (32 atoms/block)
    const int EBS = ((EB + 7) / 8) * 8;             // swizzled grid (multiple of 8)
    const int PB = (E + PCHUNK - 1) / PCHUNK;       // pooling blocks

    float* xout  = (float*)d_out;                 // [E,64]
    float* gfeat = xout + (size_t)E * DDIM;       // [16,64]

    // workspace layout
    char* w = (char*)d_ws;
    float* tt       = (float*)w;  w += sizeof(float) * 2 * NTYPES * DDIM;
    float* w2u      = (float*)w;  w += sizeof(float) * 2 * DDIM * DDIM;
    float* b2u      = (float*)w;  w += sizeof(float) * 2 * DDIM;
    w = (char*)(((uintptr_t)w + 15) & ~(uintptr_t)15);
    // MFMA weight fragments (hi/lo bf16), 2048 uint4 = 32KB each
    uint4* fW2u     = (uint4*)w;  w += 2048 * sizeof(uint4);
    uint4* fU1b     = (uint4*)w;  w += 2048 * sizeof(uint4);
    uint4* fU2      = (uint4*)w;  w += 2048 * sizeof(uint4);
    uint4* fP       = (uint4*)w;  w += 2048 * sizeof(uint4);
    int*   cnt      = (int*)w;    w += sizeof(int) * E;
    int*   offs     = (int*)w;    w += sizeof(int) * (E + 1);
    int*   cursor   = (int*)w;    w += sizeof(int) * E;
    int*   bt       = (int*)w;    w += sizeof(int) * E;
    int*   bsum     = (int*)w;    w += sizeof(int) * 1024;
    int*   bpre     = (int*)w;    w += sizeof(int) * 1024;
    int*   srclist  = (int*)w;    w += sizeof(int) * BE;
    w = (char*)(((uintptr_t)w + 15) & ~(uintptr_t)15);
    float* pd       = (float*)w;  w += sizeof(float) * (size_t)E * DDIM;
    uint4* ps       = (uint4*)w;  w += sizeof(unsigned short) * (size_t)E * DDIM;
    float* pa       = (float*)w;  w += sizeof(float) * (size_t)N * DDIM;
    float* qa       = (float*)w;  w += sizeof(float) * (size_t)N * DDIM;
    float* na       = (float*)w;  w += sizeof(float) * (size_t)N;
    w = (char*)(((uintptr_t)w + 15) & ~(uintptr_t)15);
    // optional second proj buffers (fused-proj path)
    float* pd2      = (float*)w;  w += sizeof(float) * (size_t)E * DDIM;
    uint4* ps2      = (uint4*)w;  w += sizeof(unsigned short) * (size_t)E * DDIM;
    bool fuse_proj = ((size_t)(w - (char*)d_ws) <= ws_size);

    const int* row  = edge_index;
    const int* col  = edge_index + E;
    const int* bsrc = bond_edge_index;
    const int* bdst = bond_edge_index + BE;

    // CSR build
    hipMemsetAsync(cnt, 0, (size_t)E * sizeof(int), stream);
    count_k<<<(BE + 255) / 256, 256, 0, stream>>>(bdst, cnt, BE);
    bsum_k<<<NB, 256, 0, stream>>>(cnt, bsum, E);
    bscan_k<<<1, 1024, 0, stream>>>(bsum, bpre, NB);
    offs_k<<<NB, 256, 0, stream>>>(cnt, bpre, offs, cursor, E);
    scatter_k<<<(BE + 255) / 256, 256, 0, stream>>>(bsrc, bdst, cursor, srclist, BE);

    // constants: bond-type embeddings + fused mm weights + MFMA B-fragments
    tt2_k<<<2 * NTYPES, 64, 0, stream>>>(emb, mw1, mb1, tt);
    fuse_k<<<2 * 64, 64, 0, stream>>>(mw2, mb2, uw1, w2u, b2u);
    packall_k<<<64, 64, 0, stream>>>(w2u, uw1, uw2, mw1, fW2u, fU1b, fU2, fP);

    // atom projections, then bond init + layer-0 proj
    atom_proj_k<<<AB, 256, 0, stream>>>(AF, iw1, pa, qa, na, N);
    bond_init2_k<<<EBS, 512, 0, stream>>>(AF, row, col, pa, qa, na, ib1, iw2, ib2,
                                          mw1 /* layer 0 */, xout, bt, pd, ps, E);

    if (fuse_proj) {
        // layer 0: fused next-layer proj -> pd2/ps2
        layer_k<<<EBS, 512, 0, stream>>>(
            xout, pd, ps, tt, bt, offs, srclist, cnt,
            fW2u, b2u, fU1b, ub1, fU2, ub2,
            fP, pd2, ps2, E);
        // layer 1: no proj
        layer_k<<<EBS, 512, 0, stream>>>(
            xout, pd2, ps2, tt + NTYPES * DDIM, bt, offs, srclist, cnt,
            fW2u + 1024, b2u + DDIM, fU1b + 1024, ub1 + DDIM,
            fU2 + 1024, ub2 + DDIM,
            nullptr, nullptr, nullptr, E);
    } else {
        for (int l = 0; l < 2; ++l) {
            if (l > 0)
                proj_k<<<EB, 256, 0, stream>>>(xout, mw1 + (size_t)l * 192 * 64, pd, ps, E);
            layer_k<<<EBS, 512, 0, stream>>>(
                xout, pd, ps, tt + (size_t)l * NTYPES * DDIM, bt, offs, srclist, cnt,
                fW2u + (size_t)l * 1024, b2u + (size_t)l * DDIM,
                fU1b + (size_t)l * 1024, ub1 + (size_t)l * DDIM,
                fU2 + (size_t)l * 1024, ub2 + (size_t)l * DDIM,
                nullptr, nullptr, nullptr, E);
        }
    }

    hipMemsetAsync(gfeat, 0, NGRAPHS * DDIM * sizeof(float), stream);
    pool_k<<<PB, 256, 0, stream>>>(xout, row, batch, gfeat, E);
    pool_final_k<<<NGRAPHS, 64, 0, stream>>>(row, batch, gfeat, E);
}

// Round 2
// 319.582 us; speedup vs baseline: 1.1802x; 1.0610x over previous
//
#include <hip/hip_runtime.h>
#include <cstdint>
#include <cstddef>

#define HDIM 128
#define DDIM 64
#define NTYPES 5
#define NGRAPHS 16
#define PCHUNK 128   // edges per pooling block
#define EPB 64       // edges per block (one per lane)
#define APW 8        // atoms per wave in atom_proj

typedef __attribute__((ext_vector_type(8))) short short8;   // 8 bf16
typedef __attribute__((ext_vector_type(4))) float f32x4;

static __device__ __forceinline__ short8 as_s8(uint4 u) {
    return __builtin_bit_cast(short8, u);
}

// fast silu: v_rcp_f32 (rel err ~1e-7) instead of precise-division sequence
static __device__ __forceinline__ float silu_f(float v) {
    return v * __builtin_amdgcn_rcpf(1.0f + __expf(-v));
}

static __device__ __forceinline__ float4 ld4(const float* p) {
    return *reinterpret_cast<const float4*>(p);
}

static __device__ __forceinline__ void st4(float* p, float4 v) {
    *reinterpret_cast<float4*>(p) = v;
}

static __device__ __forceinline__ float4 add4(float4 a, float4 b) {
    return make_float4(a.x + b.x, a.y + b.y, a.z + b.z, a.w + b.w);
}

static __device__ __forceinline__ void silu_acc4(float4& s, float4 v) {
    s.x += silu_f(v.x);
    s.y += silu_f(v.y);
    s.z += silu_f(v.z);
    s.w += silu_f(v.w);
}

// ---- bf16 pack/unpack (round-to-nearest-even; feature j0+0 in low half) ----
static __device__ __forceinline__ unsigned int bf16r(float f) {
    unsigned int u = __float_as_uint(f);
    return (u + 0x7FFFu + ((u >> 16) & 1u)) >> 16;
}
static __device__ __forceinline__ uint4 pack8(const float* f) {
    uint4 r;
    r.x = bf16r(f[0]) | (bf16r(f[1]) << 16);
    r.y = bf16r(f[2]) | (bf16r(f[3]) << 16);
    r.z = bf16r(f[4]) | (bf16r(f[5]) << 16);
    r.w = bf16r(f[6]) | (bf16r(f[7]) << 16);
    return r;
}
static __device__ __forceinline__ void unpack8(uint4 u, float4& a, float4& b) {
    a.x = __uint_as_float(u.x << 16);
    a.y = __uint_as_float(u.x & 0xFFFF0000u);
    a.z = __uint_as_float(u.y << 16);
    a.w = __uint_as_float(u.y & 0xFFFF0000u);
    b.x = __uint_as_float(u.z << 16);
    b.y = __uint_as_float(u.z & 0xFFFF0000u);
    b.z = __uint_as_float(u.w << 16);
    b.w = __uint_as_float(u.w & 0xFFFF0000u);
}

// split fp32 -> bf16 hi + bf16 lo (lo = v - float(hi)); hi+lo ~ 16 mantissa bits
static __device__ __forceinline__ void hilo8(const float* f, uint4& h, uint4& lo) {
    h = pack8(f);
    float4 a, b;
    unpack8(h, a, b);
    float g[8] = {f[0] - a.x, f[1] - a.y, f[2] - a.z, f[3] - a.w,
                  f[4] - b.x, f[5] - b.y, f[6] - b.z, f[7] - b.w};
    lo = pack8(g);
}

// XCD-affinity swizzle (heuristic blk%8 -> XCD round-robin; validated r7:
// layer_k FETCH 82 -> 25.7 MB).
static __device__ __forceinline__ int xcd_logical_block() {
    int chunk = (int)(gridDim.x >> 3);
    return (int)(blockIdx.x & 7) * chunk + (int)(blockIdx.x >> 3);
}

// ---------------- CSR build ----------------
__global__ void __launch_bounds__(256) count_k(const int* __restrict__ bdst,
                                               int* __restrict__ cnt, int BE) {
    int i = blockIdx.x * 256 + threadIdx.x;
    if (i < BE)
        __hip_atomic_fetch_add(&cnt[bdst[i]], 1, __ATOMIC_RELAXED, __HIP_MEMORY_SCOPE_AGENT);
}

__global__ void __launch_bounds__(256) bsum_k(const int* __restrict__ cnt,
                                              int* __restrict__ bsum, int E) {
    __shared__ int red[256];
    int t = threadIdx.x;
    int i = blockIdx.x * 256 + t;
    red[t] = (i < E) ? cnt[i] : 0;
    __syncthreads();
    #pragma unroll
    for (int off = 128; off > 0; off >>= 1) {
        if (t < off) red[t] += red[t + off];
        __syncthreads();
    }
    if (t == 0) bsum[blockIdx.x] = red[0];
}

__global__ void __launch_bounds__(1024) bscan_k(const int* __restrict__ bsum,
                                                int* __restrict__ bpre, int NB) {
    __shared__ int sh[1024];
    int t = threadIdx.x;
    int v0 = (t < NB) ? bsum[t] : 0;
    sh[t] = v0;
    __syncthreads();
    for (int off = 1; off < 1024; off <<= 1) {
        int v = (t >= off) ? sh[t - off] : 0;
        __syncthreads();
        sh[t] += v;
        __syncthreads();
    }
    if (t < NB) bpre[t] = sh[t] - v0;
}

__global__ void __launch_bounds__(256) offs_k(const int* __restrict__ cnt,
                                              const int* __restrict__ bpre,
                                              int* __restrict__ offs,
                                              int* __restrict__ cursor, int E) {
    __shared__ int sh[256];
    int t = threadIdx.x;
    int i = blockIdx.x * 256 + t;
    int v0 = (i < E) ? cnt[i] : 0;
    sh[t] = v0;
    __syncthreads();
    for (int off = 1; off < 256; off <<= 1) {
        int v = (t >= off) ? sh[t - off] : 0;
        __syncthreads();
        sh[t] += v;
        __syncthreads();
    }
    int ex = sh[t] - v0 + bpre[blockIdx.x];
    if (i < E) { offs[i] = ex; cursor[i] = ex; }
    if (i == E - 1) offs[E] = ex + v0;
}

__global__ void __launch_bounds__(256) scatter_k(const int* __restrict__ bsrc,
                                                 const int* __restrict__ bdst,
                                                 int* __restrict__ cursor,
                                                 int* __restrict__ srclist, int BE) {
    int i = blockIdx.x * 256 + threadIdx.x;
    if (i < BE) {
        int d = bdst[i];
        int p = __hip_atomic_fetch_add(&cursor[d], 1, __ATOMIC_RELAXED,
                                       __HIP_MEMORY_SCOPE_AGENT);
        srclist[p] = bsrc[i];
    }
}

// tt for BOTH layers
__global__ void __launch_bounds__(64) tt2_k(const float* __restrict__ emb,
                                            const float* __restrict__ mw1,
                                            const float* __restrict__ mb1,
                                            float* __restrict__ tt) {
    int b = blockIdx.x;
    int l = b / NTYPES, t = b % NTYPES, j = threadIdx.x;
    const float* embl = emb + (size_t)l * NTYPES * DDIM + (size_t)t * DDIM;
    const float* w1 = mw1 + (size_t)l * 192 * DDIM;
    float s = mb1[l * DDIM + j];
    #pragma unroll 8
    for (int k = 0; k < DDIM; ++k)
        s = fmaf(embl[k], w1[(HDIM + k) * DDIM + j], s);
    tt[(size_t)b * DDIM + j] = s;
}

// Fused weights: W2u[l] = mw2[l] @ uw1[l][0:64]; b2u[l] = mb2[l] @ uw1[l][0:64].
__global__ void __launch_bounds__(64) fuse_k(const float* __restrict__ mw2,
                                             const float* __restrict__ mb2,
                                             const float* __restrict__ uw1,
                                             float* __restrict__ w2u,
                                             float* __restrict__ b2u) {
    int l = blockIdx.x >> 6, k = blockIdx.x & 63, j = threadIdx.x;
    const float* w2 = mw2 + (size_t)l * DDIM * DDIM;
    const float* u1 = uw1 + (size_t)l * 128 * DDIM;   // rows 0..63 = mm part
    float s = 0.f;
    #pragma unroll 8
    for (int t = 0; t < DDIM; ++t)
        s = fmaf(w2[k * DDIM + t], u1[(size_t)t * DDIM + j], s);
    w2u[(size_t)l * DDIM * DDIM + (size_t)k * DDIM + j] = s;
    if (k == 0) {
        float b = 0.f;
        #pragma unroll 8
        for (int t = 0; t < DDIM; ++t)
            b = fmaf(mb2[l * DDIM + t], u1[(size_t)t * DDIM + j], b);
        b2u[l * DDIM + j] = b;
    }
}

// ---------------- MFMA fragment machinery ----------------
// B-frag pack layout for mfma_f32_16x16x32_bf16 (B is K32 x N16):
//   lane l holds B[ks*32 + (l>>4)*8 + i][jt*16 + (l&15)], i=0..7, as 8 bf16.
// Buffer index: ((jt*2+ks)*64 + lane)*2 + {0=hi,1=lo}.  One 64x64 matrix = 1024 uint4.
__global__ void __launch_bounds__(64) packall_k(const float* __restrict__ w2u,
                                                const float* __restrict__ uw1,
                                                const float* __restrict__ uw2,
                                                const float* __restrict__ mw1,
                                                const float* __restrict__ iw2,
                                                uint4* __restrict__ fw2u,
                                                uint4* __restrict__ fu1b,
                                                uint4* __restrict__ fu2,
                                                uint4* __restrict__ fp,
                                                uint4* __restrict__ fiw2,
                                                uint4* __restrict__ fp0) {
    int b = blockIdx.x;
    int mat = b >> 3, jt = (b >> 1) & 3, ks = b & 1, l = threadIdx.x;
    const float* src;
    uint4* dst;
    switch (mat) {
        case 0: src = w2u;                         dst = fw2u;        break;  // layer0 W2u
        case 1: src = w2u + 4096;                  dst = fw2u + 1024; break;  // layer1 W2u
        case 2: src = uw1 + 64 * 64;               dst = fu1b;        break;  // layer0 uw1[64:128]
        case 3: src = uw1 + 128 * 64 + 64 * 64;    dst = fu1b + 1024; break;  // layer1 uw1[64:128]
        case 4: src = uw2;                         dst = fu2;         break;  // layer0 uw2
        case 5: src = uw2 + 4096;                  dst = fu2 + 1024;  break;  // layer1 uw2
        case 6: src = mw1 + (size_t)192 * 64;      dst = fp;          break;  // layer1 mw1[0:64]   (pd part)
        case 7: src = mw1 + (size_t)192 * 64 + 64 * 64; dst = fp + 1024; break; // layer1 mw1[64:128] (ps part)
        case 8: src = iw2;                         dst = fiw2;        break;  // bond-init layer2
        case 9: src = mw1;                         dst = fp0;         break;  // layer0 mw1[0:64]   (pd part)
        default: src = mw1 + (size_t)64 * 64;      dst = fp0 + 1024;  break;  // layer0 mw1[64:128] (ps part)
    }
    int k0 = ks * 32 + (l >> 4) * 8;
    int j = jt * 16 + (l & 15);
    float f[8];
    #pragma unroll
    for (int i = 0; i < 8; ++i) f[i] = src[(size_t)(k0 + i) * 64 + j];
    uint4 h, lo;
    hilo8(f, h, lo);
    size_t di = ((size_t)(jt * 2 + ks) * 64 + l) * 2;
    dst[di] = h;
    dst[di + 1] = lo;
}

// LDS A-tile: [64 rows][8 slots of 16B] bf16, XOR-swizzled within the row so the
// 128B-stride fragment reads don't 16-way bank-conflict (G4).
static __device__ __forceinline__ int slotIdx(int row, int slot) {
    return row * 8 + (slot ^ (row & 7));
}

// A-frag (M16 x K32): lane l holds A[rowBase + (l&15)][ks*32 + (l>>4)*8 + i], i=0..7.
static __device__ __forceinline__ short8 ldFragA(const uint4* buf, int rowBase, int lane, int ks) {
    int row = rowBase + (lane & 15);
    int slot = ks * 4 + (lane >> 4);
    return as_s8(buf[slotIdx(row, slot)]);
}

static __device__ __forceinline__ void loadB(const uint4* __restrict__ frag, int jt, int lane,
                                             short8& h0, short8& h1, short8& l0, short8& l1) {
    const uint4* p0 = frag + ((size_t)(jt * 2 + 0) * 64 + lane) * 2;
    const uint4* p1 = frag + ((size_t)(jt * 2 + 1) * 64 + lane) * 2;
    h0 = as_s8(p0[0]); l0 = as_s8(p0[1]);
    h1 = as_s8(p1[0]); l1 = as_s8(p1[1]);
}

// one 16x16 output tile, K=64, split-precision: Ahi*Bhi + Alo*Bhi + Ahi*Blo
static __device__ __forceinline__ f32x4 gemm_tile(const uint4* Ahi, const uint4* Alo,
        int rowBase, int lane,
        short8 bh0, short8 bh1, short8 bl0, short8 bl1, f32x4 acc) {
    short8 ah0 = ldFragA(Ahi, rowBase, lane, 0);
    short8 ah1 = ldFragA(Ahi, rowBase, lane, 1);
    short8 al0 = ldFragA(Alo, rowBase, lane, 0);
    short8 al1 = ldFragA(Alo, rowBase, lane, 1);
    acc = __builtin_amdgcn_mfma_f32_16x16x32_bf16(ah0, bh0, acc, 0, 0, 0);
    acc = __builtin_amdgcn_mfma_f32_16x16x32_bf16(ah1, bh1, acc, 0, 0, 0);
    acc = __builtin_amdgcn_mfma_f32_16x16x32_bf16(al0, bh0, acc, 0, 0, 0);
    acc = __builtin_amdgcn_mfma_f32_16x16x32_bf16(al1, bh1, acc, 0, 0, 0);
    acc = __builtin_amdgcn_mfma_f32_16x16x32_bf16(ah0, bl0, acc, 0, 0, 0);
    acc = __builtin_amdgcn_mfma_f32_16x16x32_bf16(ah1, bl1, acc, 0, 0, 0);
    return acc;
}

// ---------------- atom-side projection: wave-per-8-atoms, lane = feature ----------------
__global__ void __launch_bounds__(256) atom_proj_k(
    const float* __restrict__ AF, const float* __restrict__ iw1,
    float* __restrict__ pa, float* __restrict__ qa, float* __restrict__ na, int N) {
    int lane = threadIdx.x & 63;
    int w = __builtin_amdgcn_readfirstlane((int)(threadIdx.x >> 6));
    int abase = blockIdx.x * (4 * APW) + w * APW;
    if (abase >= N) return;

    float accp[APW], accq[APW], nrm[APW];
    #pragma unroll
    for (int a = 0; a < APW; ++a) { accp[a] = 0.f; accq[a] = 0.f; nrm[a] = 0.f; }

    #pragma unroll 4
    for (int k = 0; k < HDIM; k += 4) {
        float wt[4], wb[4];
        #pragma unroll
        for (int kk = 0; kk < 4; ++kk) {
            wt[kk] = iw1[(size_t)(k + kk) * DDIM + lane];
            wb[kk] = iw1[(size_t)(HDIM + k + kk) * DDIM + lane];
        }
        #pragma unroll
        for (int a = 0; a < APW; ++a) {
            int aa = min(abase + a, N - 1);           // wave-uniform
            float4 hv = ld4(AF + (size_t)aa * HDIM + k);
            accp[a] = fmaf(hv.x, wt[0], accp[a]);
            accp[a] = fmaf(hv.y, wt[1], accp[a]);
            accp[a] = fmaf(hv.z, wt[2], accp[a]);
            accp[a] = fmaf(hv.w, wt[3], accp[a]);
            accq[a] = fmaf(hv.x, wb[0], accq[a]);
            accq[a] = fmaf(hv.y, wb[1], accq[a]);
            accq[a] = fmaf(hv.z, wb[2], accq[a]);
            accq[a] = fmaf(hv.w, wb[3], accq[a]);
            nrm[a] = fmaf(hv.x, hv.x, nrm[a]);
            nrm[a] = fmaf(hv.y, hv.y, nrm[a]);
            nrm[a] = fmaf(hv.z, hv.z, nrm[a]);
            nrm[a] = fmaf(hv.w, hv.w, nrm[a]);
        }
    }
    #pragma unroll
    for (int a = 0; a < APW; ++a) {
        int atom = abase + a;
        if (atom < N) {
            pa[(size_t)atom * DDIM + lane] = accp[a];
            qa[(size_t)atom * DDIM + lane] = accq[a];
            if (lane == 0) na[atom] = sqrtf(nrm[a]);
        }
    }
}

// ---------------- bond init (MFMA version) ----------------
// 512 threads = 8 waves, block = 64 bonds.
// P0: (dl=tid>>3, q=tid&7): h = silu(pa[r]+qa[c]+b1) -> hi/lo LDS; dot via shfl.
// P1: x = h@iw2 + b2 (MFMA, 12/wave); store fp32 x; stage x hi/lo.
// P2: pd = x@mw1_l0[0:64] (fp32), ps = bf16(x@mw1_l0[64:128])  (24 mfma/wave).
__global__ void __launch_bounds__(512, 4) bond_init2_k(
    const float* __restrict__ AF, const int* __restrict__ row, const int* __restrict__ col,
    const float* __restrict__ pa, const float* __restrict__ qa, const float* __restrict__ na,
    const float* __restrict__ b1, const uint4* __restrict__ fW2, const float* __restrict__ b2,
    const uint4* __restrict__ fP0,
    float* __restrict__ x, int* __restrict__ bt,
    float* __restrict__ pd, uint4* __restrict__ ps, int E) {
    __shared__ uint4 sAhi[512];   // h, then ps staging (hi)
    __shared__ uint4 sAlo[512];   //                    (lo)
    __shared__ uint4 sXhi[512];   // x                  (hi)
    __shared__ uint4 sXlo[512];   //                    (lo)
    int nEB = (E + EPB - 1) / EPB;
    int lb = xcd_logical_block();
    if (lb >= nEB) return;
    int tid = threadIdx.x;
    int lane = tid & 63;
    int w = __builtin_amdgcn_readfirstlane((int)(tid >> 6));   // 0..7
    int e0 = lb * EPB;

    // ---- P0: gather atoms, silu, classify ----
    {
        int dl = tid >> 3, q = tid & 7;
        int d = e0 + dl;
        bool ok = d < E;
        int dd = ok ? d : 0;
        int r = row[dd], c = col[dd];
        int jq = q * 8;

        // dot partial over AF[.][16q .. 16q+16)
        const float* hi = AF + (size_t)r * HDIM + q * 16;
        const float* hj = AF + (size_t)c * HDIM + q * 16;
        float dt = 0.f;
        #pragma unroll
        for (int k = 0; k < 16; k += 4) {
            float4 a4 = ld4(hi + k), b4 = ld4(hj + k);
            dt += a4.x * b4.x + a4.y * b4.y + a4.z * b4.z + a4.w * b4.w;
        }
        // reduce across the 8 lanes of this bond (lanes (dl&7)*8 + 0..7)
        dt += __shfl_xor(dt, 1, 64);
        dt += __shfl_xor(dt, 2, 64);
        dt += __shfl_xor(dt, 4, 64);
        if (q == 0 && ok) {
            float nr = fmaxf(na[r], 1e-8f), nc = fmaxf(na[c], 1e-8f);
            float sim = dt / (nr * nc);
            int t = 0;
            if (sim > 0.8f) t = 1;
            if (sim > 0.9f) t = 2;
            if (sim < 0.3f) t = 3;
            bt[d] = t;
        }

        // h slice = silu(pa[r] + qa[c] + b1)
        const float* pr = pa + (size_t)r * DDIM + jq;
        const float* qc = qa + (size_t)c * DDIM + jq;
        float4 p0 = ld4(pr + 0), p1 = ld4(pr + 4);
        float4 q0 = ld4(qc + 0), q1 = ld4(qc + 4);
        float hv[8];
        hv[0] = silu_f(p0.x + q0.x + b1[jq + 0]);
        hv[1] = silu_f(p0.y + q0.y + b1[jq + 1]);
        hv[2] = silu_f(p0.z + q0.z + b1[jq + 2]);
        hv[3] = silu_f(p0.w + q0.w + b1[jq + 3]);
        hv[4] = silu_f(p1.x + q1.x + b1[jq + 4]);
        hv[5] = silu_f(p1.y + q1.y + b1[jq + 5]);
        hv[6] = silu_f(p1.z + q1.z + b1[jq + 6]);
        hv[7] = silu_f(p1.w + q1.w + b1[jq + 7]);
        if (!ok) {
            #pragma unroll
            for (int i = 0; i < 8; ++i) hv[i] = 0.f;
        }
        uint4 h4, l4;
        hilo8(hv, h4, l4);
        int si = slotIdx(dl, q);
        sAhi[si] = h4; sAlo[si] = l4;
    }
    // preload W2 frags (independent of LDS; overlaps barrier wait)
    int jt = w & 3, mh = w >> 2;
    short8 W2h0, W2h1, W2l0, W2l1;
    loadB(fW2, jt, lane, W2h0, W2h1, W2l0, W2l1);
    __syncthreads();

    // ---- P1: x = h@iw2 + b2 ----
    int rb0 = mh * 32, rb1 = mh * 32 + 16;
    f32x4 z4 = {0.f, 0.f, 0.f, 0.f};
    f32x4 acc0 = z4, acc1 = z4;
    acc0 = gemm_tile(sAhi, sAlo, rb0, lane, W2h0, W2h1, W2l0, W2l1, acc0);
    acc1 = gemm_tile(sAhi, sAlo, rb1, lane, W2h0, W2h1, W2l0, W2l1, acc1);
    int j = jt * 16 + (lane & 15);
    float b2j = b2[j];
    unsigned short* hX = (unsigned short*)sXhi;
    unsigned short* lX = (unsigned short*)sXlo;
    #pragma unroll
    for (int r = 0; r < 4; ++r) {
        int rowi = rb0 + (lane >> 4) * 4 + r;
        int e = e0 + rowi;
        float xn = acc0[r] + b2j;
        if (e < E) x[(size_t)e * DDIM + j] = xn;
        unsigned int hb = bf16r(xn);
        float lov = xn - __uint_as_float(hb << 16);
        int ui = (rowi * 8 + ((j >> 3) ^ (rowi & 7))) * 8 + (j & 7);
        hX[ui] = (unsigned short)hb;
        lX[ui] = (unsigned short)bf16r(lov);
    }
    #pragma unroll
    for (int r = 0; r < 4; ++r) {
        int rowi = rb1 + (lane >> 4) * 4 + r;
        int e = e0 + rowi;
        float xn = acc1[r] + b2j;
        if (e < E) x[(size_t)e * DDIM + j] = xn;
        unsigned int hb = bf16r(xn);
        float lov = xn - __uint_as_float(hb << 16);
        int ui = (rowi * 8 + ((j >> 3) ^ (rowi & 7))) * 8 + (j & 7);
        hX[ui] = (unsigned short)hb;
        lX[ui] = (unsigned short)bf16r(lov);
    }
    __syncthreads();    // x staged; also orders P1 h-reads before P2 sA-writes

    // ---- P2: layer-0 proj. wave w -> 16-col strip of 128-wide output.
    const uint4* fPw = (w < 4) ? fP0 : (fP0 + 1024);
    int jp = w & 3;
    short8 Ph0, Ph1, Pl0, Pl1;
    loadB(fPw, jp, lane, Ph0, Ph1, Pl0, Pl1);
    f32x4 q0 = z4, q1 = z4, q2 = z4, q3 = z4;
    q0 = gemm_tile(sXhi, sXlo, 0,  lane, Ph0, Ph1, Pl0, Pl1, q0);
    q1 = gemm_tile(sXhi, sXlo, 16, lane, Ph0, Ph1, Pl0, Pl1, q1);
    q2 = gemm_tile(sXhi, sXlo, 32, lane, Ph0, Ph1, Pl0, Pl1, q2);
    q3 = gemm_tile(sXhi, sXlo, 48, lane, Ph0, Ph1, Pl0, Pl1, q3);
    unsigned short* hA = (unsigned short*)sAhi;
    if (w < 4) {
        int jd = jp * 16 + (lane & 15);
        #pragma unroll
        for (int mt = 0; mt < 4; ++mt) {
            f32x4 qq = (mt == 0) ? q0 : (mt == 1) ? q1 : (mt == 2) ? q2 : q3;
            #pragma unroll
            for (int r = 0; r < 4; ++r) {
                int rowi = mt * 16 + (lane >> 4) * 4 + r;
                int e = e0 + rowi;
                if (e < E) pd[(size_t)e * DDIM + jd] = qq[r];
            }
        }
    } else {
        int js = jp * 16 + (lane & 15);
        #pragma unroll
        for (int mt = 0; mt < 4; ++mt) {
            f32x4 qq = (mt == 0) ? q0 : (mt == 1) ? q1 : (mt == 2) ? q2 : q3;
            #pragma unroll
            for (int r = 0; r < 4; ++r) {
                int rowi = mt * 16 + (lane >> 4) * 4 + r;
                int ui = (rowi * 8 + ((js >> 3) ^ (rowi & 7))) * 8 + (js & 7);
                hA[ui] = (unsigned short)bf16r(qq[r]);
            }
        }
    }
    __syncthreads();
    {
        int dl = tid >> 3, q = tid & 7;
        int d = e0 + dl;
        if (d < E) ps[(size_t)d * 8 + q] = sAhi[slotIdx(dl, q)];
    }
}

// proj (x from global) — fallback path only (used if ws too small for pd2/ps2)
__global__ void __launch_bounds__(256) proj_k(const float* __restrict__ x,
                                              const float* __restrict__ w1 /*[192][64]*/,
                                              float* __restrict__ pd, uint4* __restrict__ ps,
                                              int E) {
    int lane = threadIdx.x & 63;
    int w = __builtin_amdgcn_readfirstlane((int)(threadIdx.x >> 6));
    int e = blockIdx.x * EPB + lane;
    bool ok = e < E;
    int eidx = ok ? e : 0;
    int j0 = w * 16;
    const float* xr = x + (size_t)eidx * DDIM;

    float apd[16], aps[16];
    #pragma unroll
    for (int jj = 0; jj < 16; ++jj) { apd[jj] = 0.f; aps[jj] = 0.f; }
    #pragma unroll 2
    for (int c = 0; c < 16; ++c) {
        float4 v = ld4(xr + c * 4);
        float xv[4] = {v.x, v.y, v.z, v.w};
        #pragma unroll
        for (int kk = 0; kk < 4; ++kk) {
            int k = c * 4 + kk;
            const float* wd = w1 + (size_t)k * DDIM + j0;
            const float* wsv = w1 + (size_t)(DDIM + k) * DDIM + j0;
            #pragma unroll
            for (int jj = 0; jj < 16; ++jj) {
                apd[jj] = fmaf(xv[kk], wd[jj], apd[jj]);
                aps[jj] = fmaf(xv[kk], wsv[jj], aps[jj]);
            }
        }
    }
    if (ok) {
        float* pr = pd + (size_t)e * DDIM + j0;
        st4(pr + 0,  make_float4(apd[0],  apd[1],  apd[2],  apd[3]));
        st4(pr + 4,  make_float4(apd[4],  apd[5],  apd[6],  apd[7]));
        st4(pr + 8,  make_float4(apd[8],  apd[9],  apd[10], apd[11]));
        st4(pr + 12, make_float4(apd[12], apd[13], apd[14], apd[15]));
        ps[(size_t)e * 8 + 2 * w + 0] = pack8(aps + 0);
        ps[(size_t)e * 8 + 2 * w + 1] = pack8(aps + 8);
    }
}

// ---------------- fused gather + update (+ optional next-layer proj), MFMA version ----
// 512 threads = 8 waves, block = 64 bonds.
// P1: gather s (bf16 ps, fp32 acc) -> inv-scaled hi/lo bf16 in LDS; stage x hi/lo.
// P2: h = silu((inv*s)@W2u + x@Uw1b + ub1 + degflag*b2u)   [24 mfma/wave]
// P3: xnew = x + h@Uw2 + ub2; store; stage xnew hi/lo       [12 mfma/wave]
// P4 (layer0): pdn = xnew@W1d (fp32); psn = bf16(xnew@W1s)  [24 mfma/wave]
// GEMM tiling: wave w -> col-tile jt=w&3 (j=jt*16+lane&15), row-half mh=w>>2.
// D layout (m89-verified): col = lane&15, row = (lane>>4)*4 + reg.
__global__ void __launch_bounds__(512, 4) layer_k(
    float* __restrict__ x, const float* __restrict__ pd, const uint4* __restrict__ ps,
    const float* __restrict__ tt_l, const int* __restrict__ bt,
    const int* __restrict__ offs, const int* __restrict__ srclist,
    const int* __restrict__ cnt,
    const uint4* __restrict__ fW2u, const float* __restrict__ b2u,
    const uint4* __restrict__ fU1b, const float* __restrict__ ub1,
    const uint4* __restrict__ fU2, const float* __restrict__ ub2,
    const uint4* __restrict__ fP /* next-layer proj frags or nullptr */,
    float* __restrict__ pdn, uint4* __restrict__ psn, int E) {
    __shared__ uint4 sAhi[512];   // s / h / psn-staging  (hi)
    __shared__ uint4 sAlo[512];   //                      (lo)
    __shared__ uint4 sXhi[512];   // x / xnew             (hi)
    __shared__ uint4 sXlo[512];   //                      (lo)
    __shared__ float degLDS[64];  // 1.0 if deg>0 else 0.0
    int nEB = (E + EPB - 1) / EPB;
    int lb = xcd_logical_block();
    if (lb >= nEB) return;
    int tid = threadIdx.x;
    int lane = tid & 63;
    int w = __builtin_amdgcn_readfirstlane((int)(tid >> 6));   // 0..7
    int e0 = lb * EPB;

    // ---- P1: stage x + gather (8 threads per bond, 8 features each) ----
    {
        int dl = tid >> 3, q = tid & 7;
        int d = e0 + dl;
        bool ok = d < E;
        int dd = ok ? d : 0;
        int jq = q * 8;
        const float* xr = x + (size_t)dd * DDIM + jq;
        float4 xv0 = ld4(xr + 0), xv1 = ld4(xr + 4);   // issued early, used late
        int dc = cnt[dd];
        const float* pr = pd + (size_t)dd * DDIM + jq;
        const float* tp = tt_l + (size_t)bt[dd] * DDIM + jq;
        float4 b0 = add4(ld4(pr + 0), ld4(tp + 0));
        float4 b1 = add4(ld4(pr + 4), ld4(tp + 4));
        float4 s0 = make_float4(0, 0, 0, 0), s1 = s0;
        int p0 = ok ? offs[d] : 0, p1 = ok ? offs[d + 1] : 0;
        int p = p0;
        for (; p + 4 <= p1; p += 4) {
            uint4 u0 = ps[(size_t)srclist[p + 0] * 8 + q];
            uint4 u1 = ps[(size_t)srclist[p + 1] * 8 + q];
            uint4 u2 = ps[(size_t)srclist[p + 2] * 8 + q];
            uint4 u3 = ps[(size_t)srclist[p + 3] * 8 + q];
            float4 a, b;
            unpack8(u0, a, b);
            silu_acc4(s0, add4(b0, a));
            silu_acc4(s1, add4(b1, b));
            unpack8(u1, a, b);
            silu_acc4(s0, add4(b0, a));
            silu_acc4(s1, add4(b1, b));
            unpack8(u2, a, b);
            silu_acc4(s0, add4(b0, a));
            silu_acc4(s1, add4(b1, b));
            unpack8(u3, a, b);
            silu_acc4(s0, add4(b0, a));
            silu_acc4(s1, add4(b1, b));
        }
        for (; p < p1; ++p) {
            uint4 u0 = ps[(size_t)srclist[p] * 8 + q];
            float4 a, b;
            unpack8(u0, a, b);
            silu_acc4(s0, add4(b0, a));
            silu_acc4(s1, add4(b1, b));
        }
        float inv = 1.0f / fmaxf((float)dc, 1.0f);
        float sv[8] = {s0.x * inv, s0.y * inv, s0.z * inv, s0.w * inv,
                       s1.x * inv, s1.y * inv, s1.z * inv, s1.w * inv};
        float xf[8] = {xv0.x, xv0.y, xv0.z, xv0.w, xv1.x, xv1.y, xv1.z, xv1.w};
        if (!ok) {
            #pragma unroll
            for (int i = 0; i < 8; ++i) { sv[i] = 0.f; xf[i] = 0.f; }
        }
        uint4 h4, l4;
        int si = slotIdx(dl, q);
        hilo8(sv, h4, l4);
        sAhi[si] = h4; sAlo[si] = l4;
        hilo8(xf, h4, l4);
        sXhi[si] = h4; sXlo[si] = l4;
        if (q == 0) degLDS[dl] = (ok && dc > 0) ? 1.0f : 0.0f;
    }
    // preload loop-invariant B-frags (independent of LDS; overlaps barrier wait)
    int jt = w & 3, mh = w >> 2;
    short8 A2h0, A2h1, A2l0, A2l1;   // W2u
    short8 U1h0, U1h1, U1l0, U1l1;   // Uw1b
    loadB(fW2u, jt, lane, A2h0, A2h1, A2l0, A2l1);
    loadB(fU1b, jt, lane, U1h0, U1h1, U1l0, U1l1);
    __syncthreads();

    // ---- P2: h = silu((inv*s)@W2u + x@Uw1b + bias) ----
    int rb0 = mh * 32, rb1 = mh * 32 + 16;
    f32x4 z4 = {0.f, 0.f, 0.f, 0.f};
    f32x4 acc0 = z4, acc1 = z4;
    acc0 = gemm_tile(sAhi, sAlo, rb0, lane, A2h0, A2h1, A2l0, A2l1, acc0);
    acc0 = gemm_tile(sXhi, sXlo, rb0, lane, U1h0, U1h1, U1l0, U1l1, acc0);
    acc1 = gemm_tile(sAhi, sAlo, rb1, lane, A2h0, A2h1, A2l0, A2l1, acc1);
    acc1 = gemm_tile(sXhi, sXlo, rb1, lane, U1h0, U1h1, U1l0, U1l1, acc1);
    __syncthreads();                       // all s/x fragment reads done
    int j = jt * 16 + (lane & 15);
    float ub1j = ub1[j], b2uj = b2u[j];
    unsigned short* hA = (unsigned short*)sAhi;
    unsigned short* lA = (unsigned short*)sAlo;
    #pragma unroll
    for (int r = 0; r < 4; ++r) {
        int row = rb0 + (lane >> 4) * 4 + r;
        float hv = silu_f(acc0[r] + ub1j + degLDS[row] * b2uj);
        unsigned int hb = bf16r(hv);
        float lov = hv - __uint_as_float(hb << 16);
        int ui = (row * 8 + ((j >> 3) ^ (row & 7))) * 8 + (j & 7);
        hA[ui] = (unsigned short)hb;
        lA[ui] = (unsigned short)bf16r(lov);
    }
    #pragma unroll
    for (int r = 0; r < 4; ++r) {
        int row = rb1 + (lane >> 4) * 4 + r;
        float hv = silu_f(acc1[r] + ub1j + degLDS[row] * b2uj);
        unsigned int hb = bf16r(hv);
        float lov = hv - __uint_as_float(hb << 16);
        int ui = (row * 8 + ((j >> 3) ^ (row & 7))) * 8 + (j & 7);
        hA[ui] = (unsigned short)hb;
        lA[ui] = (unsigned short)bf16r(lov);
    }
    __syncthreads();                       // h staged

    // ---- P3: o = h@Uw2 + ub2; xnew = x + o ----
    short8 U2h0, U2h1, U2l0, U2l1;
    loadB(fU2, jt, lane, U2h0, U2h1, U2l0, U2l1);
    f32x4 o0 = z4, o1 = z4;
    o0 = gemm_tile(sAhi, sAlo, rb0, lane, U2h0, U2h1, U2l0, U2l1, o0);
    o1 = gemm_tile(sAhi, sAlo, rb1, lane, U2h0, U2h1, U2l0, U2l1, o1);
    float ub2j = ub2[j];
    bool haveP = (fP != nullptr);
    unsigned short* hX = (unsigned short*)sXhi;
    unsigned short* lX = (unsigned short*)sXlo;
    #pragma unroll
    for (int r = 0; r < 4; ++r) {
        int row = rb0 + (lane >> 4) * 4 + r;
        int e = e0 + row;
        float xvv = (e < E) ? x[(size_t)e * DDIM + j] : 0.f;
        float xn = xvv + o0[r] + ub2j;
        if (e < E) x[(size_t)e * DDIM + j] = xn;
        if (haveP) {
            unsigned int hb = bf16r(xn);
            float lov = xn - __uint_as_float(hb << 16);
            int ui = (row * 8 + ((j >> 3) ^ (row & 7))) * 8 + (j & 7);
            hX[ui] = (unsigned short)hb;
            lX[ui] = (unsigned short)bf16r(lov);
        }
    }
    #pragma unroll
    for (int r = 0; r < 4; ++r) {
        int row = rb1 + (lane >> 4) * 4 + r;
        int e = e0 + row;
        float xvv = (e < E) ? x[(size_t)e * DDIM + j] : 0.f;
        float xn = xvv + o1[r] + ub2j;
        if (e < E) x[(size_t)e * DDIM + j] = xn;
        if (haveP) {
            unsigned int hb = bf16r(xn);
            float lov = xn - __uint_as_float(hb << 16);
            int ui = (row * 8 + ((j >> 3) ^ (row & 7))) * 8 + (j & 7);
            hX[ui] = (unsigned short)hb;
            lX[ui] = (unsigned short)bf16r(lov);
        }
    }
    if (!haveP) return;
    __syncthreads();    // xnew staged; orders P3 A-reads before P4 A-writes

    // ---- P4: next-layer proj. wave w -> 16-col strip of the 128-wide output.
    const uint4* fPw = (w < 4) ? fP : (fP + 1024);
    int jp = w & 3;
    short8 Ph0, Ph1, Pl0, Pl1;
    loadB(fPw, jp, lane, Ph0, Ph1, Pl0, Pl1);
    f32x4 q0 = z4, q1 = z4, q2 = z4, q3 = z4;
    q0 = gemm_tile(sXhi, sXlo, 0,  lane, Ph0, Ph1, Pl0, Pl1, q0);
    q1 = gemm_tile(sXhi, sXlo, 16, lane, Ph0, Ph1, Pl0, Pl1, q1);
    q2 = gemm_tile(sXhi, sXlo, 32, lane, Ph0, Ph1, Pl0, Pl1, q2);
    q3 = gemm_tile(sXhi, sXlo, 48, lane, Ph0, Ph1, Pl0, Pl1, q3);
    if (w < 4) {
        // pdn (fp32), cols jp*16 + (lane&15)
        int jd = jp * 16 + (lane & 15);
        #pragma unroll
        for (int mt = 0; mt < 4; ++mt) {
            f32x4 qq = (mt == 0) ? q0 : (mt == 1) ? q1 : (mt == 2) ? q2 : q3;
            #pragma unroll
            for (int r = 0; r < 4; ++r) {
                int row = mt * 16 + (lane >> 4) * 4 + r;
                int e = e0 + row;
                if (e < E) pdn[(size_t)e * DDIM + jd] = qq[r];
            }
        }
    } else {
        // psn (bf16): stage into sAhi rows then repack as uint4
        int js = jp * 16 + (lane & 15);
        #pragma unroll
        for (int mt = 0; mt < 4; ++mt) {
            f32x4 qq = (mt == 0) ? q0 : (mt == 1) ? q1 : (mt == 2) ? q2 : q3;
            #pragma unroll
            for (int r = 0; r < 4; ++r) {
                int row = mt * 16 + (lane >> 4) * 4 + r;
                int ui = (row * 8 + ((js >> 3) ^ (row & 7))) * 8 + (js & 7);
                hA[ui] = (unsigned short)bf16r(qq[r]);
            }
        }
    }
    __syncthreads();
    {
        int dl = tid >> 3, q = tid & 7;
        int d = e0 + dl;
        if (d < E) psn[(size_t)d * 8 + q] = sAhi[slotIdx(dl, q)];
    }
}

// ---------------- pooling ----------------
__global__ void __launch_bounds__(256) pool_k(
    const float* __restrict__ x, const int* __restrict__ row,
    const int* __restrict__ batch, float* __restrict__ gfeat, int E) {
    int lane = threadIdx.x & 63;
    int esub = threadIdx.x >> 6;       // 0..3
    int e0 = blockIdx.x * PCHUNK;
    int e1 = min(e0 + PCHUNK, E);
    float sum = 0.f;
    int cur = -1;
    for (int e = e0 + esub; e < e1; e += 4) {
        int g = batch[row[e]];         // wave-uniform -> scalar load
        if (g != cur) {
            if (cur >= 0)
                __hip_atomic_fetch_add(&gfeat[cur * DDIM + lane], sum,
                                       __ATOMIC_RELAXED, __HIP_MEMORY_SCOPE_AGENT);
            cur = g;
            sum = 0.f;
        }
        sum += x[(size_t)e * DDIM + lane];
    }
    if (cur >= 0)
        __hip_atomic_fetch_add(&gfeat[cur * DDIM + lane], sum,
                               __ATOMIC_RELAXED, __HIP_MEMORY_SCOPE_AGENT);
}

static __device__ __forceinline__ int lower_bound_bb(const int* __restrict__ row,
                                                     const int* __restrict__ batch,
                                                     int E, int g) {
    int lo = 0, hi = E;
    while (lo < hi) {
        int m = (lo + hi) >> 1;
        if (batch[row[m]] < g) lo = m + 1; else hi = m;
    }
    return lo;
}

__global__ void __launch_bounds__(64) pool_final_k(
    const int* __restrict__ row, const int* __restrict__ batch,
    float* __restrict__ gfeat, int E) {
    int g = blockIdx.x, j = threadIdx.x;
    int s = lower_bound_bb(row, batch, E, g);
    int t = lower_bound_bb(row, batch, E, g + 1);
    float cnt = fmaxf((float)(t - s), 1.0f);
    gfeat[g * DDIM + j] /= cnt;
}

extern "C" void kernel_launch(void* const* d_in, const int* in_sizes, int n_in,
                              void* d_out, int out_size, void* d_ws, size_t ws_size,
                              hipStream_t stream) {
    (void)n_in; (void)out_size;
    const float* AF    = (const float*)d_in[0];
    const int*   batch = (const int*)d_in[3];
    const int*   edge_index      = (const int*)d_in[4];
    const int*   bond_edge_index = (const int*)d_in[5];
    const float* iw1 = (const float*)d_in[6];
    const float* ib1 = (const float*)d_in[7];
    const float* iw2 = (const float*)d_in[8];
    const float* ib2 = (const float*)d_in[9];
    const float* emb = (const float*)d_in[10];
    const float* mw1 = (const float*)d_in[11];
    const float* mb1 = (const float*)d_in[12];
    const float* mw2 = (const float*)d_in[13];
    const float* mb2 = (const float*)d_in[14];
    const float* uw1 = (const float*)d_in[15];
    const float* ub1 = (const float*)d_in[16];
    const float* uw2 = (const float*)d_in[17];
    const float* ub2 = (const float*)d_in[18];

    const int N  = in_sizes[0] / HDIM;
    const int E  = in_sizes[4] / 2;
    const int BE = in_sizes[5] / 2;
    const int NB = (E + 255) / 256;
    const int EB = (E + EPB - 1) / EPB;
    const int AB = (N + 4 * APW - 1) / (4 * APW);   // atom blocks (32 atoms/block)
    const int EBS = ((EB + 7) / 8) * 8;             // swizzled grid (multiple of 8)
    const int PB = (E + PCHUNK - 1) / PCHUNK;       // pooling blocks

    float* xout  = (float*)d_out;                 // [E,64]
    float* gfeat = xout + (size_t)E * DDIM;       // [16,64]

    // workspace layout
    char* w = (char*)d_ws;
    float* tt       = (float*)w;  w += sizeof(float) * 2 * NTYPES * DDIM;
    float* w2u      = (float*)w;  w += sizeof(float) * 2 * DDIM * DDIM;
    float* b2u      = (float*)w;  w += sizeof(float) * 2 * DDIM;
    w = (char*)(((uintptr_t)w + 15) & ~(uintptr_t)15);
    // MFMA weight fragments (hi/lo bf16)
    uint4* fW2u     = (uint4*)w;  w += 2048 * sizeof(uint4);
    uint4* fU1b     = (uint4*)w;  w += 2048 * sizeof(uint4);
    uint4* fU2      = (uint4*)w;  w += 2048 * sizeof(uint4);
    uint4* fP       = (uint4*)w;  w += 2048 * sizeof(uint4);
    uint4* fIw2     = (uint4*)w;  w += 1024 * sizeof(uint4);
    uint4* fP0      = (uint4*)w;  w += 2048 * sizeof(uint4);
    int*   cnt      = (int*)w;    w += sizeof(int) * E;
    int*   offs     = (int*)w;    w += sizeof(int) * (E + 1);
    int*   cursor   = (int*)w;    w += sizeof(int) * E;
    int*   bt       = (int*)w;    w += sizeof(int) * E;
    int*   bsum     = (int*)w;    w += sizeof(int) * 1024;
    int*   bpre     = (int*)w;    w += sizeof(int) * 1024;
    int*   srclist  = (int*)w;    w += sizeof(int) * BE;
    w = (char*)(((uintptr_t)w + 15) & ~(uintptr_t)15);
    float* pd       = (float*)w;  w += sizeof(float) * (size_t)E * DDIM;
    uint4* ps       = (uint4*)w;  w += sizeof(unsigned short) * (size_t)E * DDIM;
    float* pa       = (float*)w;  w += sizeof(float) * (size_t)N * DDIM;
    float* qa       = (float*)w;  w += sizeof(float) * (size_t)N * DDIM;
    float* na       = (float*)w;  w += sizeof(float) * (size_t)N;
    w = (char*)(((uintptr_t)w + 15) & ~(uintptr_t)15);
    // optional second proj buffers (fused-proj path)
    float* pd2      = (float*)w;  w += sizeof(float) * (size_t)E * DDIM;
    uint4* ps2      = (uint4*)w;  w += sizeof(unsigned short) * (size_t)E * DDIM;
    bool fuse_proj = ((size_t)(w - (char*)d_ws) <= ws_size);

    const int* row  = edge_index;
    const int* col  = edge_index + E;
    const int* bsrc = bond_edge_index;
    const int* bdst = bond_edge_index + BE;

    // CSR build
    hipMemsetAsync(cnt, 0, (size_t)E * sizeof(int), stream);
    count_k<<<(BE + 255) / 256, 256, 0, stream>>>(bdst, cnt, BE);
    bsum_k<<<NB, 256, 0, stream>>>(cnt, bsum, E);
    bscan_k<<<1, 1024, 0, stream>>>(bsum, bpre, NB);
    offs_k<<<NB, 256, 0, stream>>>(cnt, bpre, offs, cursor, E);
    scatter_k<<<(BE + 255) / 256, 256, 0, stream>>>(bsrc, bdst, cursor, srclist, BE);

    // constants: bond-type embeddings + fused mm weights + MFMA B-fragments
    tt2_k<<<2 * NTYPES, 64, 0, stream>>>(emb, mw1, mb1, tt);
    fuse_k<<<2 * 64, 64, 0, stream>>>(mw2, mb2, uw1, w2u, b2u);
    packall_k<<<88, 64, 0, stream>>>(w2u, uw1, uw2, mw1, iw2,
                                     fW2u, fU1b, fU2, fP, fIw2, fP0);

    // atom projections, then bond init + layer-0 proj (MFMA)
    atom_proj_k<<<AB, 256, 0, stream>>>(AF, iw1, pa, qa, na, N);
    bond_init2_k<<<EBS, 512, 0, stream>>>(AF, row, col, pa, qa, na, ib1, fIw2, ib2,
                                          fP0, xout, bt, pd, ps, E);

    if (fuse_proj) {
        // layer 0: fused next-layer proj -> pd2/ps2
        layer_k<<<EBS, 512, 0, stream>>>(
            xout, pd, ps, tt, bt, offs, srclist, cnt,
            fW2u, b2u, fU1b, ub1, fU2, ub2,
            fP, pd2, ps2, E);
        // layer 1: no proj
        layer_k<<<EBS, 512, 0, stream>>>(
            xout, pd2, ps2, tt + NTYPES * DDIM, bt, offs, srclist, cnt,
            fW2u + 1024, b2u + DDIM, fU1b + 1024, ub1 + DDIM,
            fU2 + 1024, ub2 + DDIM,
            nullptr, nullptr, nullptr, E);
    } else {
        for (int l = 0; l < 2; ++l) {
            if (l > 0)
                proj_k<<<EB, 256, 0, stream>>>(xout, mw1 + (size_t)l * 192 * 64, pd, ps, E);
            layer_k<<<EBS, 512, 0, stream>>>(
                xout, pd, ps, tt + (size_t)l * NTYPES * DDIM, bt, offs, srclist, cnt,
                fW2u + (size_t)l * 1024, b2u + (size_t)l * DDIM,
                fU1b + (size_t)l * 1024, ub1 + (size_t)l * DDIM,
                fU2 + (size_t)l * 1024, ub2 + (size_t)l * DDIM,
                nullptr, nullptr, nullptr, E);
        }
    }

    hipMemsetAsync(gfeat, 0, NGRAPHS * DDIM * sizeof(float), stream);
    pool_k<<<PB, 256, 0, stream>>>(xout, row, batch, gfeat, E);
    pool_final_k<<<NGRAPHS, 64, 0, stream>>>(row, batch, gfeat, E);
}